// Round 3
// baseline (505.553 us; speedup 1.0000x reference)
//
#include <hip/hip_runtime.h>
#include <stdint.h>

typedef short short8 __attribute__((ext_vector_type(8)));
typedef float floatx4 __attribute__((ext_vector_type(4)));

static __device__ __forceinline__ float bflo(unsigned int u) {
    union { unsigned int i; float f; } v; v.i = u << 16; return v.f;
}
static __device__ __forceinline__ float bfhi(unsigned int u) {
    union { unsigned int i; float f; } v; v.i = u & 0xffff0000u; return v.f;
}
static __device__ __forceinline__ unsigned short f2bf(float f) {
    union { float f; unsigned int i; } v; v.f = f;
    unsigned int u = v.i;
    unsigned int r = u + 0x7fffu + ((u >> 16) & 1u);
    return (unsigned short)(r >> 16);
}

// ---------------- CSR build ----------------

__global__ void k_init_deg(int* degi, int N) {
    int i = blockIdx.x * 256 + threadIdx.x;
    if (i < N) degi[i] = 0;
}

__global__ void k_count(const int* __restrict__ dst, int* degi, int E, int N) {
    int e = blockIdx.x * 256 + threadIdx.x;
    if (e < E) {
        unsigned int d = (unsigned int)dst[e];
        if (d < (unsigned int)N) atomicAdd(&degi[d], 1);
    }
}

// 1024 elements per block, 256 threads
__global__ void k_block_sum(const int* __restrict__ degi, int* blk, int N) {
    __shared__ int s[256];
    int base = blockIdx.x * 1024;
    int t = threadIdx.x;
    int i0 = base + t * 4;
    int sum = 0;
#pragma unroll
    for (int j = 0; j < 4; j++) { int i = i0 + j; if (i < N) sum += degi[i]; }
    s[t] = sum; __syncthreads();
    for (int off = 128; off > 0; off >>= 1) {
        if (t < off) s[t] += s[t + off];
        __syncthreads();
    }
    if (t == 0) blk[blockIdx.x] = s[0];
}

// single block: exclusive scan of per-block sums (NB <= 256)
__global__ void k_scan_blk(int* blk, int NB) {
    __shared__ int s[256];
    int t = threadIdx.x;
    int v = (t < NB) ? blk[t] : 0;
    s[t] = v; __syncthreads();
    for (int off = 1; off < 256; off <<= 1) {
        int x = (t >= off) ? s[t - off] : 0;
        __syncthreads();
        s[t] += x;
        __syncthreads();
    }
    if (t < NB) blk[t] = s[t] - v;  // exclusive
}

__global__ void k_scan_final(const int* __restrict__ degi, const int* __restrict__ blk,
                             int* row_start, int* cursor, float* dinv, int N) {
    __shared__ int s[256];
    int base = blockIdx.x * 1024;
    int t = threadIdx.x;
    int i0 = base + t * 4;
    int d0 = 0, d1 = 0, d2 = 0, d3 = 0;
    if (i0 + 3 < N) {
        int4 q = *(const int4*)(degi + i0);
        d0 = q.x; d1 = q.y; d2 = q.z; d3 = q.w;
    } else {
        if (i0 < N) d0 = degi[i0];
        if (i0 + 1 < N) d1 = degi[i0 + 1];
        if (i0 + 2 < N) d2 = degi[i0 + 2];
        if (i0 + 3 < N) d3 = degi[i0 + 3];
    }
    int tot = d0 + d1 + d2 + d3;
    s[t] = tot; __syncthreads();
    for (int off = 1; off < 256; off <<= 1) {
        int x = (t >= off) ? s[t - off] : 0;
        __syncthreads();
        s[t] += x;
        __syncthreads();
    }
    int excl = s[t] - tot + blk[blockIdx.x];
    int o0 = excl, o1 = excl + d0, o2 = excl + d0 + d1, o3 = excl + d0 + d1 + d2;
    if (i0 < N)     { row_start[i0]     = o0; cursor[i0]     = o0; dinv[i0]     = rsqrtf((float)(d0 + 1)); }
    if (i0 + 1 < N) { row_start[i0 + 1] = o1; cursor[i0 + 1] = o1; dinv[i0 + 1] = rsqrtf((float)(d1 + 1)); }
    if (i0 + 2 < N) { row_start[i0 + 2] = o2; cursor[i0 + 2] = o2; dinv[i0 + 2] = rsqrtf((float)(d2 + 1)); }
    if (i0 + 3 < N) { row_start[i0 + 3] = o3; cursor[i0 + 3] = o3; dinv[i0 + 3] = rsqrtf((float)(d3 + 1)); }
}

__global__ void k_scatter(const int* __restrict__ src, const int* __restrict__ dst,
                          int* cursor, int* __restrict__ csr, int E, int N) {
    int e = blockIdx.x * 256 + threadIdx.x;
    if (e < E) {
        unsigned int d = (unsigned int)dst[e];
        unsigned int sv = (unsigned int)src[e];
        if (d < (unsigned int)N && sv < (unsigned int)N) {
            int p = atomicAdd(&cursor[d], 1);
            if ((unsigned int)p < (unsigned int)E) csr[p] = (int)sv;
        }
    }
}

// ---------------- GEMM: out[M,NOUT] = X[M,128] @ W[128,NOUT], K=128 ----------------
// X: fp32 (layer 1) or bf16 (layers 2/3); W,bias: fp32; compute: bf16 MFMA, fp32 acc.
// epilogue: optionally * dinv[row]; optionally + bias. out: bf16 (intermediate) or fp32 (final).

template <int NOUT, bool SCALE, bool BIAS, bool XF32, bool OUTF32>
__global__ __launch_bounds__(256, 2) void k_gemm(
    const void* __restrict__ Xv, const float* __restrict__ W,
    const float* __restrict__ bias, const float* __restrict__ dinv,
    void* __restrict__ outv, int M) {
    // W staged transposed in LDS as bf16: Wl[n*136 + k]; stride 136 (272B ≡ 4 banks
    // mod 32 -> 2-way conflict on ds_read_b128 = free per m136)
    __shared__ __align__(16) unsigned short Wl[NOUT * 136];
    int t = threadIdx.x;
    for (int idx = t; idx < 128 * NOUT; idx += 256) {
        int k = idx / NOUT, n = idx % NOUT;  // W row-major [k][n] -> coalesced fp32 read
        Wl[n * 136 + k] = f2bf(W[idx]);
    }
    __syncthreads();

    int wave = t >> 6, lane = t & 63;
    int quad = lane >> 4, l16 = lane & 15;
    int m0 = blockIdx.x * 64 + wave * 16;
    int mr = m0 + l16;
    int mrc = mr < M ? mr : M - 1;  // clamp tail loads

    constexpr int NT = NOUT / 16;
    floatx4 acc[NT];
#pragma unroll
    for (int i = 0; i < NT; i++) acc[i] = (floatx4){0.f, 0.f, 0.f, 0.f};

#pragma unroll
    for (int kc = 0; kc < 4; kc++) {
        // A frag: lane holds A[m=l16][k=kc*32+quad*8 .. +7]
        short8 a;
        if (XF32) {
            const float* X = (const float*)Xv;
            const float* p = X + (size_t)mrc * 128 + kc * 32 + quad * 8;
            float4 xa = *(const float4*)p;
            float4 xb = *(const float4*)(p + 4);
            a[0] = (short)f2bf(xa.x); a[1] = (short)f2bf(xa.y);
            a[2] = (short)f2bf(xa.z); a[3] = (short)f2bf(xa.w);
            a[4] = (short)f2bf(xb.x); a[5] = (short)f2bf(xb.y);
            a[6] = (short)f2bf(xb.z); a[7] = (short)f2bf(xb.w);
        } else {
            const unsigned short* X = (const unsigned short*)Xv;
            a = *(const short8*)(X + (size_t)mrc * 128 + kc * 32 + quad * 8);
        }
#pragma unroll
        for (int nt = 0; nt < NT; nt++) {
            short8 b = *(const short8*)(&Wl[(nt * 16 + l16) * 136 + kc * 32 + quad * 8]);
            acc[nt] = __builtin_amdgcn_mfma_f32_16x16x32_bf16(a, b, acc[nt], 0, 0, 0);
        }
    }

    // C layout: col = l16, row (within 16) = quad*4 + i
#pragma unroll
    for (int i = 0; i < 4; i++) {
        int r = m0 + quad * 4 + i;
        if (r >= M) continue;
        float sc = SCALE ? dinv[r] : 1.0f;
#pragma unroll
        for (int nt = 0; nt < NT; nt++) {
            int n = nt * 16 + l16;
            float v = acc[nt][i] * sc;
            if (BIAS) v += bias[n];
            if (OUTF32) {
                ((float*)outv)[(size_t)r * NOUT + n] = v;
            } else {
                ((unsigned short*)outv)[(size_t)r * NOUT + n] = f2bf(v);
            }
        }
    }
}

// ---------------- Aggregation: out[d] = relu(dinv[d]*(Hs[d] + sum_nbr Hs[src]) + b) ----------------
// one wave per node; lane handles 2 channels (128ch = 64 lanes * 2); row read = 256B coalesced
// row_end comes from cursor[] (post-scatter value == row end). Hs/out bf16, bias fp32.

__global__ __launch_bounds__(256, 4) void k_aggregate(
    const unsigned short* __restrict__ Hs, const int* __restrict__ csr,
    const int* __restrict__ row_start, const int* __restrict__ row_end,
    const float* __restrict__ dinv, const float* __restrict__ bias,
    unsigned short* __restrict__ out, int N, int E) {
    int wave = threadIdx.x >> 6, lane = threadIdx.x & 63;
    int node = blockIdx.x * 4 + wave;
    if (node >= N) return;
    int ch = lane * 2;
    int Nm1 = N - 1;

    unsigned int u = *(const unsigned int*)(Hs + (size_t)node * 128 + ch);  // self-loop term
    float a0 = bflo(u), a1 = bfhi(u);

    int start = row_start[node];
    int end = row_end[node];
    if (start < 0) start = 0;
    if (end > E) end = E;
    int e = start;
    for (; e + 4 <= end; e += 4) {
        int s0 = min(max(csr[e], 0), Nm1);
        int s1 = min(max(csr[e + 1], 0), Nm1);
        int s2 = min(max(csr[e + 2], 0), Nm1);
        int s3 = min(max(csr[e + 3], 0), Nm1);
        unsigned int u0 = *(const unsigned int*)(Hs + (size_t)s0 * 128 + ch);
        unsigned int u1 = *(const unsigned int*)(Hs + (size_t)s1 * 128 + ch);
        unsigned int u2 = *(const unsigned int*)(Hs + (size_t)s2 * 128 + ch);
        unsigned int u3 = *(const unsigned int*)(Hs + (size_t)s3 * 128 + ch);
        a0 += bflo(u0) + bflo(u1) + bflo(u2) + bflo(u3);
        a1 += bfhi(u0) + bfhi(u1) + bfhi(u2) + bfhi(u3);
    }
    for (; e < end; e++) {
        int s0 = min(max(csr[e], 0), Nm1);
        unsigned int u0 = *(const unsigned int*)(Hs + (size_t)s0 * 128 + ch);
        a0 += bflo(u0);
        a1 += bfhi(u0);
    }

    float di = dinv[node];
    float r0 = fmaxf(fmaf(di, a0, bias[ch]), 0.f);
    float r1 = fmaxf(fmaf(di, a1, bias[ch + 1]), 0.f);
    unsigned int pk = (unsigned int)f2bf(r0) | ((unsigned int)f2bf(r1) << 16);
    *(unsigned int*)(out + (size_t)node * 128 + ch) = pk;
}

// ---------------- launch ----------------

extern "C" void kernel_launch(void* const* d_in, const int* in_sizes, int n_in,
                              void* d_out, int out_size, void* d_ws, size_t ws_size,
                              hipStream_t stream) {
    const float* x  = (const float*)d_in[0];
    const int* ei   = (const int*)d_in[1];
    const float* W1 = (const float*)d_in[2];
    const float* b1 = (const float*)d_in[3];
    const float* W2 = (const float*)d_in[4];
    const float* b2 = (const float*)d_in[5];
    const float* Wf = (const float*)d_in[6];
    const float* bf = (const float*)d_in[7];

    int N = in_sizes[0] / 128;
    int E = in_sizes[1] / 2;
    const int* src = ei;
    const int* dst = ei + E;

    // workspace budget check (deterministic per session -> graph-safe)
    size_t need = 0;
    auto pad = [](size_t b) { return (b + 255) & ~(size_t)255; };
    size_t o_degi = need; need += pad((size_t)N * 4);
    size_t o_rs   = need; need += pad((size_t)N * 4);
    size_t o_cur  = need; need += pad((size_t)N * 4);
    size_t o_dinv = need; need += pad((size_t)N * 4);
    size_t o_blk  = need; need += pad(1024 * 4);
    size_t o_csr  = need; need += pad((size_t)E * 4);
    size_t o_hs   = need; need += pad((size_t)N * 128 * 2);
    size_t o_a    = need; need += pad((size_t)N * 128 * 2);
    if (ws_size < need) return;  // diagnostic: zero output (absmax == max|ref|) instead of OOB fault

    char* ws = (char*)d_ws;
    int* degi      = (int*)(ws + o_degi);
    int* row_start = (int*)(ws + o_rs);
    int* cursor    = (int*)(ws + o_cur);
    float* dinv    = (float*)(ws + o_dinv);
    int* blk       = (int*)(ws + o_blk);
    int* csr       = (int*)(ws + o_csr);
    unsigned short* Hs = (unsigned short*)(ws + o_hs);
    unsigned short* A  = (unsigned short*)(ws + o_a);

    int NB = (N + 1023) / 1024;
    k_init_deg<<<(N + 255) / 256, 256, 0, stream>>>(degi, N);
    k_count<<<(E + 255) / 256, 256, 0, stream>>>(dst, degi, E, N);
    k_block_sum<<<NB, 256, 0, stream>>>(degi, blk, N);
    k_scan_blk<<<1, 256, 0, stream>>>(blk, NB);
    k_scan_final<<<NB, 256, 0, stream>>>(degi, blk, row_start, cursor, dinv, N);
    k_scatter<<<(E + 255) / 256, 256, 0, stream>>>(src, dst, cursor, csr, E, N);

    int GB = (N + 63) / 64;
    // layer 1: Hs = (x@W1)*dinv ; A = relu(dinv*(agg Hs) + b1)
    k_gemm<128, true, false, true, false><<<GB, 256, 0, stream>>>(x, W1, nullptr, dinv, Hs, N);
    k_aggregate<<<(N + 3) / 4, 256, 0, stream>>>(Hs, csr, row_start, cursor, dinv, b1, A, N, E);
    // layer 2
    k_gemm<128, true, false, false, false><<<GB, 256, 0, stream>>>(A, W2, nullptr, dinv, Hs, N);
    k_aggregate<<<(N + 3) / 4, 256, 0, stream>>>(Hs, csr, row_start, cursor, dinv, b2, A, N, E);
    // final linear head (fp32 out)
    k_gemm<64, false, true, false, true><<<GB, 256, 0, stream>>>(A, Wf, bf, nullptr, d_out, N);
}

// Round 4
// 356.571 us; speedup vs baseline: 1.4178x; 1.4178x over previous
//
#include <hip/hip_runtime.h>
#include <stdint.h>

typedef short short8 __attribute__((ext_vector_type(8)));
typedef float floatx4 __attribute__((ext_vector_type(4)));

#define BK 256  // nodes per bucket (== k_fine block size)

static __device__ __forceinline__ float bflo(unsigned int u) {
    union { unsigned int i; float f; } v; v.i = u << 16; return v.f;
}
static __device__ __forceinline__ float bfhi(unsigned int u) {
    union { unsigned int i; float f; } v; v.i = u & 0xffff0000u; return v.f;
}
static __device__ __forceinline__ unsigned short f2bf(float f) {
    union { float f; unsigned int i; } v; v.f = f;
    unsigned int u = v.i;
    unsigned int r = u + 0x7fffu + ((u >> 16) & 1u);
    return (unsigned short)(r >> 16);
}

// ---------------- CSR build: two-level counting sort by dst ----------------

__global__ void k_zero_cnt(int* bucket_cnt, int K) {
    int i = blockIdx.x * 256 + threadIdx.x;
    if (i < K) bucket_cnt[i] = 0;
}

// coarse histogram of dst>>8 (LDS-staged; ~K global atomics per block)
__global__ __launch_bounds__(256) void k_hist(const int* __restrict__ dst, int* bucket_cnt,
                                              int E, int N, int K) {
    __shared__ int h[512];
    int t = threadIdx.x;
    for (int i = t; i < K; i += 256) h[i] = 0;
    __syncthreads();
    int per = (E + gridDim.x - 1) / gridDim.x;
    int lo = blockIdx.x * per, hi = min(lo + per, E);
    for (int e = lo + t; e < hi; e += 256) {
        unsigned int d = (unsigned int)dst[e];
        if (d < (unsigned int)N) atomicAdd(&h[d >> 8], 1);
    }
    __syncthreads();
    for (int i = t; i < K; i += 256) if (h[i]) atomicAdd(&bucket_cnt[i], h[i]);
}

// single block: exclusive scan of K bucket counts (K <= 512); init cursors + sentinel
__global__ void k_scanK(const int* __restrict__ bucket_cnt, int* bucket_off, int* bucket_cur,
                        int* row_start, int K, int N) {
    __shared__ int s[512];
    int t = threadIdx.x;
    int v = (t < K) ? bucket_cnt[t] : 0;
    s[t] = v; __syncthreads();
    for (int off = 1; off < 512; off <<= 1) {
        int x = (t >= off) ? s[t - off] : 0;
        __syncthreads();
        s[t] += x;
        __syncthreads();
    }
    if (t < K) { bucket_off[t] = s[t] - v; bucket_cur[t] = s[t] - v; }
    if (t == K - 1) { bucket_off[K] = s[t]; row_start[N] = s[t]; }
}

// bucket-sort edges: block reserves per-bucket ranges, writes (src,dst) pairs in
// ~128B contiguous runs per bucket instead of random 4B scatter
__global__ __launch_bounds__(256) void k_binscatter(const int* __restrict__ src,
                                                    const int* __restrict__ dst,
                                                    int* bucket_cur, uint2* __restrict__ tmp,
                                                    int E, int N, int K) {
    __shared__ int h[512];
    __shared__ int base[512];
    int t = threadIdx.x;
    for (int i = t; i < K; i += 256) h[i] = 0;
    __syncthreads();
    int per = (E + gridDim.x - 1) / gridDim.x;
    int lo = blockIdx.x * per, hi = min(lo + per, E);
    for (int e = lo + t; e < hi; e += 256) {
        unsigned int d = (unsigned int)dst[e], sv = (unsigned int)src[e];
        if (d < (unsigned int)N && sv < (unsigned int)N) atomicAdd(&h[d >> 8], 1);
    }
    __syncthreads();
    for (int i = t; i < K; i += 256) {
        int c = h[i];
        base[i] = c ? atomicAdd(&bucket_cur[i], c) : 0;
        h[i] = 0;
    }
    __syncthreads();
    for (int e = lo + t; e < hi; e += 256) {
        unsigned int d = (unsigned int)dst[e], sv = (unsigned int)src[e];
        if (d < (unsigned int)N && sv < (unsigned int)N) {
            int k = d >> 8;
            int p = base[k] + atomicAdd(&h[k], 1);
            tmp[p] = make_uint2(sv, d);
        }
    }
}

// one block per bucket: per-node degree + scan + cursors all in LDS;
// csr writes confined to a ~16KB contiguous region (L1/L2-resident)
__global__ __launch_bounds__(256) void k_fine(const uint2* __restrict__ tmp,
                                              const int* __restrict__ bucket_off,
                                              int* __restrict__ row_start, float* __restrict__ dinv,
                                              int* __restrict__ csr, int N) {
    __shared__ int deg[BK];
    __shared__ int scn[BK];
    __shared__ int cur[BK];
    int b = blockIdx.x;
    int t = threadIdx.x;
    int lo = bucket_off[b], hi = bucket_off[b + 1];
    deg[t] = 0;
    __syncthreads();
    for (int e = lo + t; e < hi; e += 256) {
        int d = tmp[e].y & (BK - 1);
        atomicAdd(&deg[d], 1);
    }
    __syncthreads();
    int v = deg[t];
    scn[t] = v; __syncthreads();
    for (int off = 1; off < 256; off <<= 1) {
        int x = (t >= off) ? scn[t - off] : 0;
        __syncthreads();
        scn[t] += x;
        __syncthreads();
    }
    int rs = lo + scn[t] - v;
    cur[t] = rs;
    int node = b * BK + t;
    if (node < N) { row_start[node] = rs; dinv[node] = rsqrtf((float)(v + 1)); }
    __syncthreads();
    for (int e = lo + t; e < hi; e += 256) {
        uint2 ed = tmp[e];
        int d = ed.y & (BK - 1);
        int p = atomicAdd(&cur[d], 1);
        csr[p] = (int)ed.x;
    }
}

// ---------------- GEMM: out[M,NOUT] = X[M,128] @ W[128,NOUT], K=128 ----------------
// X: fp32 (layer 1) or bf16; W,bias fp32; bf16 MFMA, fp32 acc.

template <int NOUT, bool SCALE, bool BIAS, bool XF32, bool OUTF32>
__global__ __launch_bounds__(256, 2) void k_gemm(
    const void* __restrict__ Xv, const float* __restrict__ W,
    const float* __restrict__ bias, const float* __restrict__ dinv,
    void* __restrict__ outv, int M) {
    __shared__ __align__(16) unsigned short Wl[NOUT * 136];
    int t = threadIdx.x;
    for (int idx = t; idx < 128 * NOUT; idx += 256) {
        int k = idx / NOUT, n = idx % NOUT;
        Wl[n * 136 + k] = f2bf(W[idx]);
    }
    __syncthreads();

    int wave = t >> 6, lane = t & 63;
    int quad = lane >> 4, l16 = lane & 15;
    int m0 = blockIdx.x * 64 + wave * 16;
    int mr = m0 + l16;
    int mrc = mr < M ? mr : M - 1;

    constexpr int NT = NOUT / 16;
    floatx4 acc[NT];
#pragma unroll
    for (int i = 0; i < NT; i++) acc[i] = (floatx4){0.f, 0.f, 0.f, 0.f};

#pragma unroll
    for (int kc = 0; kc < 4; kc++) {
        short8 a;
        if (XF32) {
            const float* X = (const float*)Xv;
            const float* p = X + (size_t)mrc * 128 + kc * 32 + quad * 8;
            float4 xa = *(const float4*)p;
            float4 xb = *(const float4*)(p + 4);
            a[0] = (short)f2bf(xa.x); a[1] = (short)f2bf(xa.y);
            a[2] = (short)f2bf(xa.z); a[3] = (short)f2bf(xa.w);
            a[4] = (short)f2bf(xb.x); a[5] = (short)f2bf(xb.y);
            a[6] = (short)f2bf(xb.z); a[7] = (short)f2bf(xb.w);
        } else {
            const unsigned short* X = (const unsigned short*)Xv;
            a = *(const short8*)(X + (size_t)mrc * 128 + kc * 32 + quad * 8);
        }
#pragma unroll
        for (int nt = 0; nt < NT; nt++) {
            short8 b = *(const short8*)(&Wl[(nt * 16 + l16) * 136 + kc * 32 + quad * 8]);
            acc[nt] = __builtin_amdgcn_mfma_f32_16x16x32_bf16(a, b, acc[nt], 0, 0, 0);
        }
    }

#pragma unroll
    for (int i = 0; i < 4; i++) {
        int r = m0 + quad * 4 + i;
        if (r >= M) continue;
        float sc = SCALE ? dinv[r] : 1.0f;
#pragma unroll
        for (int nt = 0; nt < NT; nt++) {
            int n = nt * 16 + l16;
            float v = acc[nt][i] * sc;
            if (BIAS) v += bias[n];
            if (OUTF32) {
                ((float*)outv)[(size_t)r * NOUT + n] = v;
            } else {
                ((unsigned short*)outv)[(size_t)r * NOUT + n] = f2bf(v);
            }
        }
    }
}

// ---------------- Aggregation ----------------
// out[d] = relu(dinv[d]*(Hs[d] + sum_nbr Hs[src]) + b); one wave/node, 2 ch/lane

__global__ __launch_bounds__(256, 4) void k_aggregate(
    const unsigned short* __restrict__ Hs, const int* __restrict__ csr,
    const int* __restrict__ row_start,
    const float* __restrict__ dinv, const float* __restrict__ bias,
    unsigned short* __restrict__ out, int N, int E) {
    int wave = threadIdx.x >> 6, lane = threadIdx.x & 63;
    int node = blockIdx.x * 4 + wave;
    if (node >= N) return;
    int ch = lane * 2;
    int Nm1 = N - 1;

    unsigned int u = *(const unsigned int*)(Hs + (size_t)node * 128 + ch);
    float a0 = bflo(u), a1 = bfhi(u);

    int start = row_start[node];
    int end = row_start[node + 1];
    if (start < 0) start = 0;
    if (end > E) end = E;
    int e = start;
    for (; e + 4 <= end; e += 4) {
        int s0 = min(max(csr[e], 0), Nm1);
        int s1 = min(max(csr[e + 1], 0), Nm1);
        int s2 = min(max(csr[e + 2], 0), Nm1);
        int s3 = min(max(csr[e + 3], 0), Nm1);
        unsigned int u0 = *(const unsigned int*)(Hs + (size_t)s0 * 128 + ch);
        unsigned int u1 = *(const unsigned int*)(Hs + (size_t)s1 * 128 + ch);
        unsigned int u2 = *(const unsigned int*)(Hs + (size_t)s2 * 128 + ch);
        unsigned int u3 = *(const unsigned int*)(Hs + (size_t)s3 * 128 + ch);
        a0 += bflo(u0) + bflo(u1) + bflo(u2) + bflo(u3);
        a1 += bfhi(u0) + bfhi(u1) + bfhi(u2) + bfhi(u3);
    }
    for (; e < end; e++) {
        int s0 = min(max(csr[e], 0), Nm1);
        unsigned int u0 = *(const unsigned int*)(Hs + (size_t)s0 * 128 + ch);
        a0 += bflo(u0);
        a1 += bfhi(u0);
    }

    float di = dinv[node];
    float r0 = fmaxf(fmaf(di, a0, bias[ch]), 0.f);
    float r1 = fmaxf(fmaf(di, a1, bias[ch + 1]), 0.f);
    unsigned int pk = (unsigned int)f2bf(r0) | ((unsigned int)f2bf(r1) << 16);
    *(unsigned int*)(out + (size_t)node * 128 + ch) = pk;
}

// ---------------- launch ----------------

extern "C" void kernel_launch(void* const* d_in, const int* in_sizes, int n_in,
                              void* d_out, int out_size, void* d_ws, size_t ws_size,
                              hipStream_t stream) {
    const float* x  = (const float*)d_in[0];
    const int* ei   = (const int*)d_in[1];
    const float* W1 = (const float*)d_in[2];
    const float* b1 = (const float*)d_in[3];
    const float* W2 = (const float*)d_in[4];
    const float* b2 = (const float*)d_in[5];
    const float* Wf = (const float*)d_in[6];
    const float* bf = (const float*)d_in[7];

    int N = in_sizes[0] / 128;
    int E = in_sizes[1] / 2;
    const int* src = ei;
    const int* dst = ei + E;
    int K = (N + BK - 1) / BK;  // 391 for N=100000 (<=512 assumed)

    size_t need = 0;
    auto pad = [](size_t b) { return (b + 255) & ~(size_t)255; };
    size_t o_bcnt = need; need += pad(512 * 4);
    size_t o_boff = need; need += pad(513 * 4);
    size_t o_bcur = need; need += pad(512 * 4);
    size_t o_rs   = need; need += pad(((size_t)N + 1) * 4);
    size_t o_dinv = need; need += pad((size_t)N * 4);
    size_t o_csr  = need; need += pad((size_t)E * 4);
    size_t o_hs   = need; need += pad((size_t)N * 128 * 2);
    size_t o_a    = need; need += pad((size_t)N * 128 * 2);
    if (ws_size < need) return;
    if ((size_t)E * 8 > (size_t)N * 128 * 2) return;  // tmp must fit in A (holds for this problem)

    char* ws = (char*)d_ws;
    int* bucket_cnt = (int*)(ws + o_bcnt);
    int* bucket_off = (int*)(ws + o_boff);
    int* bucket_cur = (int*)(ws + o_bcur);
    int* row_start  = (int*)(ws + o_rs);
    float* dinv     = (float*)(ws + o_dinv);
    int* csr        = (int*)(ws + o_csr);
    unsigned short* Hs = (unsigned short*)(ws + o_hs);
    unsigned short* A  = (unsigned short*)(ws + o_a);
    uint2* tmp      = (uint2*)A;  // alias: tmp dead before A's first write

    k_zero_cnt<<<(K + 255) / 256, 256, 0, stream>>>(bucket_cnt, K);
    k_hist<<<256, 256, 0, stream>>>(dst, bucket_cnt, E, N, K);
    k_scanK<<<1, 512, 0, stream>>>(bucket_cnt, bucket_off, bucket_cur, row_start, K, N);
    k_binscatter<<<256, 256, 0, stream>>>(src, dst, bucket_cur, tmp, E, N, K);
    k_fine<<<K, 256, 0, stream>>>(tmp, bucket_off, row_start, dinv, csr, N);

    int GB = (N + 63) / 64;
    k_gemm<128, true, false, true, false><<<GB, 256, 0, stream>>>(x, W1, nullptr, dinv, Hs, N);
    k_aggregate<<<(N + 3) / 4, 256, 0, stream>>>(Hs, csr, row_start, dinv, b1, A, N, E);
    k_gemm<128, true, false, false, false><<<GB, 256, 0, stream>>>(A, W2, nullptr, dinv, Hs, N);
    k_aggregate<<<(N + 3) / 4, 256, 0, stream>>>(Hs, csr, row_start, dinv, b2, A, N, E);
    k_gemm<64, false, true, false, true><<<GB, 256, 0, stream>>>(A, Wf, bf, nullptr, d_out, N);
}